// Round 15
// baseline (202.550 us; speedup 1.0000x reference)
//
#include <hip/hip_runtime.h>
#include <cmath>

// ---------------------------------------------------------------------------
// Hyperbolic MS-CNN (Poincare ball, c=1) — round 15 (r14 compile fix).
//  * MFMA convs (split bf16 hi/lo, 3 MFMAs) + fused epilogue + MREP.
//  * Depth-2 B prefetch (3-phase rotated register buffers) + nontemporal
//    B loads (L1 bypass) via native ext_vector u32x4.
// ---------------------------------------------------------------------------

#define EPSF 1e-15f
#define ATANH_CAP 0.9999999f  // 1 - 1e-7

typedef __attribute__((ext_vector_type(8))) short short8;
typedef __attribute__((ext_vector_type(4))) float f32x4;
typedef __attribute__((ext_vector_type(4))) unsigned int u32x4;

__device__ inline unsigned rne16(float f) {
  unsigned u = __float_as_uint(f);
  return (u + 0x7FFFu + ((u >> 16) & 1u)) >> 16;
}
__device__ inline float fexp2(float x) { return __builtin_amdgcn_exp2f(x); }
__device__ inline float flog2(float x) { return __builtin_amdgcn_logf(x); }
__device__ inline float frcp(float x) { return __builtin_amdgcn_rcpf(x); }

__device__ inline float atanh_over(float n) {
  float nc = fminf(n, ATANH_CAP);
  float f = 0.34657359f * flog2((1.f + nc) * frcp(1.f - nc)) * frcp(n);
  float s = 1.f + 0.33333333f * n * n;
  return (n < 0.004f) ? s : f;
}
__device__ inline float tanh_over(float n) {
  float p2 = fexp2(2.885390082f * n);  // e^{2n}
  float f = (1.f - 2.f * frcp(p2 + 1.f)) * frcp(n);
  float s = 1.f - 0.33333333f * n * n;
  return (n < 0.004f) ? s : f;
}
__device__ inline float sinh_zasinh(float q, float twozn) {
  float aq = fabsf(q);
  float t = aq + sqrtf(fmaf(aq, aq, 1.f));
  float p = fexp2(twozn * flog2(t));
  float y = 0.5f * (p - frcp(p));
  return copysignf(y, q);
}

// ---------------- merged z column norms, stage 1 ----------------------------
__global__ __launch_bounds__(256) void znorm_all_kernel(
    const float* __restrict__ z1, const float* __restrict__ z2,
    const float* __restrict__ z3, const float* __restrict__ z4,
    const float* __restrict__ zf1, const float* __restrict__ zf2,
    float* __restrict__ part) {
  const int bx = blockIdx.x;
  const float* z; int K, Nout, coff, lb;
  if (bx < 1)       { z = z1;  K = 27;   Nout = 32;   coff = 0;   lb = bx; }
  else if (bx < 2)  { z = z2;  K = 800;  Nout = 64;   coff = 32;  lb = bx - 1; }
  else if (bx < 4)  { z = z3;  K = 3136; Nout = 128;  coff = 96;  lb = bx - 2; }
  else if (bx < 6)  { z = z4;  K = 1152; Nout = 128;  coff = 224; lb = bx - 4; }
  else if (bx < 14) { z = zf1; K = 352;  Nout = 512;  coff = 352; lb = bx - 6; }
  else              { z = zf2; K = 512;  Nout = 1000; coff = 864; lb = bx - 14; }
  const int tid = threadIdx.x;
  const int col = lb * 64 + (tid & 63);
  const int kg = (blockIdx.y << 2) + (tid >> 6);
  float s = 0.f;
  if (col < Nout)
    for (int k = kg; k < K; k += 64) {
      float v = z[(size_t)k * Nout + col];
      s += v * v;
    }
  __shared__ float red[256];
  red[tid] = s;
  __syncthreads();
  if (tid < 64 && col < Nout) {
    float t = red[tid] + red[tid + 64] + red[tid + 128] + red[tid + 192];
    part[(size_t)blockIdx.y * 2048 + coff + col] = t;
  }
}
__global__ __launch_bounds__(256) void znorm_fin_kernel(
    const float* __restrict__ part, float* __restrict__ zn) {
  int c = blockIdx.x * 256 + threadIdx.x;
  float s = 0.f;
#pragma unroll
  for (int rr = 0; rr < 16; ++rr) s += part[rr * 2048 + c];
  zn[c] = sqrtf(fmaxf(s, EPSF));
}

// ---------------- z -> MFMA-fragment-ordered hi/lo bf16 (merged) ------------
template <int CIN, int CSH, int TAPS, int KK, int COUT>
__device__ inline void zfprep_body(int blk, const float* __restrict__ z,
                                   unsigned short* __restrict__ zh,
                                   unsigned short* __restrict__ zl) {
  constexpr int CPAD = 1 << CSH;
  constexpr int KP = TAPS * CPAD;
  constexpr int NT = COUT / 16;
  int t = blk * 256 + threadIdx.x;
  if (t >= KP * COUT) return;
  int k = t / COUT, n = t - k * COUT;
  int ks = k >> 5, lg = (k >> 3) & 3, i = k & 7;
  int nt = n >> 4, lm = n & 15;
  size_t e = ((size_t)(ks * NT + nt) * 64 + lg * 16 + lm) * 8 + i;
  int tap = k >> CSH, c = k & (CPAD - 1);
  float val = (c < CIN && tap < KK) ? z[(size_t)(c * KK + tap) * COUT + n] : 0.f;
  unsigned hi = rne16(val);
  float hif = __uint_as_float(hi << 16);
  unsigned lo = rne16(val - hif);
  zh[e] = (unsigned short)hi;
  zl[e] = (unsigned short)lo;
}
__global__ __launch_bounds__(256) void zfprep_all_kernel(
    const float* __restrict__ z1, const float* __restrict__ z2,
    const float* __restrict__ z3, const float* __restrict__ z4,
    unsigned short* __restrict__ zf1h, unsigned short* __restrict__ zf1l,
    unsigned short* __restrict__ zf2h, unsigned short* __restrict__ zf2l,
    unsigned short* __restrict__ zf3h, unsigned short* __restrict__ zf3l,
    unsigned short* __restrict__ zf4h, unsigned short* __restrict__ zf4l) {
  const int bx = blockIdx.x;
  if (bx < 12)        zfprep_body<3, 3, 12, 9, 32>(bx, z1, zf1h, zf1l);
  else if (bx < 212)  zfprep_body<32, 5, 25, 25, 64>(bx - 12, z2, zf2h, zf2l);
  else if (bx < 1780) zfprep_body<64, 6, 49, 49, 128>(bx - 212, z3, zf3h, zf3l);
  else                zfprep_body<128, 7, 9, 9, 128>(bx - 1780, z4, zf4h, zf4l);
}

// ---------------- merged weighted spatial means ------------------------------
__global__ __launch_bounds__(256) void wavgpool_all_kernel(
    const float* __restrict__ m1, const float* __restrict__ m2,
    const float* __restrict__ m3, const float* __restrict__ m4,
    const float* __restrict__ f1, const float* __restrict__ f2,
    const float* __restrict__ f3, const float* __restrict__ f4,
    float* __restrict__ flat) {
  const int c = blockIdx.x, b = blockIdx.y, tid = threadIdx.x;
  const float* m; const float* f; int HW, C, cl;
  if (c < 32)       { m = m1; f = f1; HW = 4096; C = 32;  cl = c; }
  else if (c < 96)  { m = m2; f = f2; HW = 1024; C = 64;  cl = c - 32; }
  else if (c < 224) { m = m3; f = f3; HW = 256;  C = 128; cl = c - 96; }
  else              { m = m4; f = f4; HW = 64;   C = 128; cl = c - 224; }
  const float* p = m + ((size_t)b * C + cl) * HW;
  const float* q = f + (size_t)b * HW;
  float s = 0.f;
  for (int i = tid; i < HW; i += 256) s += p[i] * q[i];
  __shared__ float red[256];
  red[tid] = s; __syncthreads();
  for (int st = 128; st > 0; st >>= 1) {
    if (tid < st) red[tid] += red[tid + st];
    __syncthreads();
  }
  if (tid == 0) flat[(size_t)b * 352 + c] = red[0] / (float)HW;
}

// ---------------- MFMA fused hconv + hrelu-tangent + maxpool + maps ---------
template <int CIN, int CSH, int TAPS, int K, int PAD, int COUT, int H, int W,
          int TH, int TW, int WM, int MREP, int WN, bool FLOG>
__global__ __launch_bounds__(WM * WN * 64) void hconv_mfma(
    const float* __restrict__ vin, const float* __restrict__ s2map,
    const unsigned short* __restrict__ zfh,
    const unsigned short* __restrict__ zfl,
    const float* __restrict__ r, const float* __restrict__ zn,
    float* __restrict__ mout, float* __restrict__ s2out,
    float* __restrict__ fout, float scale) {
  constexpr int NTHR = WM * WN * 64;
  constexpr int CPAD = 1 << CSH;
  constexpr int KK = K * K;
  constexpr int MT = WM * MREP * 16;
  static_assert(MT == TH * TW, "tile rows mismatch");
  constexpr int NT = COUT / 16;
  constexpr int NTW = NT / WN;
  static_assert(NTW * WN == NT, "");
  constexpr int NK = TAPS * CPAD / 32;
  static_assert(NK * 32 == TAPS * CPAD, "K-step misalign");
  constexpr int SY = TH + K - 1, SX = TW + K - 1;
  constexpr int NPOS = SY * SX;
  constexpr int RWU = (CPAD >= 32) ? (CPAD + 8) : CPAD;
  constexpr int CGR = CPAD / 8;
  constexpr int TRS = MT + 4;
  constexpr int WINU = NPOS * RWU;
  constexpr int TRU = 2 * COUT * TRS;
  constexpr int SHU = (2 * WINU > TRU) ? 2 * WINU : TRU;
  constexpr int HO = H / 2, WO = W / 2;
  constexpr int PH = TH / 2, PW = TW / 2, NPP = PH * PW;
  constexpr int CG0 = NTHR / NPP;
  constexpr int CG = (CG0 < COUT) ? CG0 : COUT;
  constexpr int CPG = COUT / CG;
  static_assert(CPG * CG == COUT, "pool split");
  constexpr int SENT = 1 << 30;

  __shared__ __align__(16) unsigned short winbuf[SHU];
  __shared__ float s2w[NPOS];
  __shared__ float gA[MT], cA[MT];
  __shared__ float c1b[COUT], shb[COUT], z2b[COUT];
  __shared__ float redw[(WN > 1) ? WN * MT : 1];
  __shared__ float pacc[NTHR];
  __shared__ int stab[NK * 4];
  unsigned short* winh = winbuf;
  unsigned short* winl = winbuf + WINU;

  const int tid = threadIdx.x;
  int bid = blockIdx.x;
  constexpr int TXC = W / TW, TYC = H / TH;
  const int tx = bid % TXC; bid /= TXC;
  const int ty = bid % TYC; const int b = bid / TYC;
  const int y0 = ty * TH, x0 = tx * TW;

  if (tid < COUT) {
    float rv = r[tid];
    float znv = zn[tid];
    float ch = coshf(2.f * rv), sh = sinhf(2.f * rv);
    c1b[tid] = 2.f * ch / znv;
    shb[tid] = sh;
    z2b[tid] = 2.f * znv;
  }
  for (int i = tid; i < NK * 4; i += NTHR) {
    int ks = i >> 2, lg2 = i & 3;
    int kbase = ks * 32 + lg2 * 8;
    int tap = kbase >> CSH, c0 = kbase & (CPAD - 1);
    int v;
    if (TAPS != KK && tap >= KK) {
      v = SENT;
    } else {
      int iy = tap / K, ix = tap - (tap / K) * K;
      v = (iy * SX + ix) * RWU + c0;
    }
    stab[i] = v;
  }
  const float* vb = vin + (size_t)b * CIN * H * W;
  if constexpr (FLOG) {
    static_assert(CIN == 3 && CPAD == 8, "FLOG expects CIN=3");
    for (int pos = tid; pos < NPOS; pos += NTHR) {
      int sy = pos / SX, sx = pos - sy * SX;
      int gy = y0 + sy - PAD, gx = x0 + sx - PAD;
      bool inb = (gy >= 0 && gy < H && gx >= 0 && gx < W);
      float v0 = 0.f, v1 = 0.f, v2 = 0.f;
      if (inb) {
        const float* gp = vb + gy * W + gx;
        v0 = gp[0];
        v1 = gp[(size_t)H * W];
        v2 = gp[(size_t)2 * H * W];
      }
      float ssr = v0 * v0 + v1 * v1 + v2 * v2;
      float n = sqrtf(fmaxf(ssr, EPSF));
      float f = atanh_over(n);
      s2w[pos] = f * f * ssr;
      float vals[8] = {f * v0, f * v1, f * v2, 0.f, 0.f, 0.f, 0.f, 0.f};
      short8 hv, lv;
#pragma unroll
      for (int j = 0; j < 8; ++j) {
        unsigned hi = rne16(vals[j]);
        float hif = __uint_as_float(hi << 16);
        unsigned lo = rne16(vals[j] - hif);
        hv[j] = (short)hi;
        lv[j] = (short)lo;
      }
      *(short8*)(winh + pos * RWU) = hv;
      *(short8*)(winl + pos * RWU) = lv;
    }
  } else {
    for (int idx = tid; idx < CGR * NPOS; idx += NTHR) {
      int pos = idx / CGR;
      int cg = idx - pos * CGR;
      int sy = pos / SX, sx = pos - sy * SX;
      int gy = y0 + sy - PAD, gx = x0 + sx - PAD;
      bool inb = (gy >= 0 && gy < H && gx >= 0 && gx < W);
      const float* gp = vb + (size_t)(cg * 8) * H * W + gy * W + gx;
      short8 hv, lv;
#pragma unroll
      for (int j = 0; j < 8; ++j) {
        float val = 0.f;
        if constexpr (CIN == CPAD) {
          if (inb) val = gp[(size_t)j * H * W];
        } else {
          if (inb && (cg * 8 + j) < CIN) val = gp[(size_t)j * H * W];
        }
        unsigned hi = rne16(val);
        float hif = __uint_as_float(hi << 16);
        unsigned lo = rne16(val - hif);
        hv[j] = (short)hi;
        lv[j] = (short)lo;
      }
      *(short8*)(winh + pos * RWU + cg * 8) = hv;
      *(short8*)(winl + pos * RWU + cg * 8) = lv;
    }
    const float* s2bp = s2map + (size_t)b * H * W;
    for (int i = tid; i < NPOS; i += NTHR) {
      int sy = i / SX, sx = i - sy * SX;
      int gy = y0 + sy - PAD, gx = x0 + sx - PAD;
      s2w[i] = (gy >= 0 && gy < H && gx >= 0 && gx < W) ? s2bp[gy * W + gx] : 0.f;
    }
  }
  __syncthreads();

  if (tid < MT) {
    int py = tid / TW, px = tid - (tid / TW) * TW;
    float s = 0.f;
    for (int iy = 0; iy < K; ++iy)
      for (int ix = 0; ix < K; ++ix)
        s += s2w[(py + iy) * SX + (px + ix)];
    float n = sqrtf(fmaxf(scale * scale * s, EPSF));
    float th = n * tanh_over(n);
    gA[tid] = th * scale * frcp(n);
    cA[tid] = th * th;
  }
  __syncthreads();

  const int w = __builtin_amdgcn_readfirstlane(tid >> 6);
  const int wm = w % WM, wn = w / WM;
  const int lane = tid & 63, lm = lane & 15, lg = lane >> 4;
  const int nt0 = wn * NTW;

  int abase[MREP];
#pragma unroll
  for (int rep = 0; rep < MREP; ++rep) {
    int m = (wm * MREP + rep) * 16 + lm;
    int py = m / TW, px = m - (m / TW) * TW;
    abase[rep] = (py * SX + px) * RWU;
  }

  f32x4 acc[MREP][NTW];
#pragma unroll
  for (int rep = 0; rep < MREP; ++rep)
#pragma unroll
    for (int j = 0; j < NTW; ++j) acc[rep][j] = (f32x4){0.f, 0.f, 0.f, 0.f};

  const unsigned short* bph = zfh + (size_t)nt0 * 512 + lane * 8;
  const unsigned short* bpl = zfl + (size_t)nt0 * 512 + lane * 8;
  constexpr size_t BSTEP = (size_t)NT * 512;

#define LOADB(BH, BL, KS)                                             \
  do {                                                                \
    const unsigned short* ph_ = bph + (size_t)(KS)*BSTEP;             \
    const unsigned short* pl_ = bpl + (size_t)(KS)*BSTEP;             \
    _Pragma("unroll") for (int j_ = 0; j_ < NTW; ++j_) {              \
      BH[j_] = __builtin_nontemporal_load((const u32x4*)(ph_ + j_ * 512)); \
      BL[j_] = __builtin_nontemporal_load((const u32x4*)(pl_ + j_ * 512)); \
    }                                                                 \
  } while (0)

#define LOADA(AH, AL, KS)                                             \
  do {                                                                \
    const int so_ = stab[(KS)*4 + lg];                                \
    bool valid_ = true;                                               \
    if constexpr (TAPS != KK) valid_ = (so_ < SENT);                  \
    _Pragma("unroll") for (int r_ = 0; r_ < MREP; ++r_) {             \
      if (valid_) {                                                   \
        const int lofs_ = abase[r_] + so_;                            \
        AH[r_] = *(const short8*)(winh + lofs_);                      \
        AL[r_] = *(const short8*)(winl + lofs_);                      \
      } else {                                                        \
        AH[r_] = (short8){};                                          \
        AL[r_] = (short8){};                                          \
      }                                                               \
    }                                                                 \
  } while (0)

#define STEPK(AH, AL, BH, BL)                                         \
  do {                                                                \
    _Pragma("unroll") for (int rep_ = 0; rep_ < MREP; ++rep_) {       \
      _Pragma("unroll") for (int j_ = 0; j_ < NTW; ++j_) {            \
        short8 bhv_ = __builtin_bit_cast(short8, BH[j_]);             \
        short8 blv_ = __builtin_bit_cast(short8, BL[j_]);             \
        acc[rep_][j_] = __builtin_amdgcn_mfma_f32_16x16x32_bf16(      \
            AH[rep_], bhv_, acc[rep_][j_], 0, 0, 0);                  \
        acc[rep_][j_] = __builtin_amdgcn_mfma_f32_16x16x32_bf16(      \
            AH[rep_], blv_, acc[rep_][j_], 0, 0, 0);                  \
        acc[rep_][j_] = __builtin_amdgcn_mfma_f32_16x16x32_bf16(      \
            AL[rep_], bhv_, acc[rep_][j_], 0, 0, 0);                  \
      }                                                               \
    }                                                                 \
  } while (0)

  {
    // 3-phase rotation: depth-2 B prefetch (LOADB ks+2 before STEPK ks)
    u32x4 BhA[NTW], BlA[NTW], BhB[NTW], BlB[NTW], BhC[NTW], BlC[NTW];
    short8 AhA[MREP], AlA[MREP], AhB[MREP], AlB[MREP], AhC[MREP], AlC[MREP];
    LOADB(BhA, BlA, 0);
    LOADA(AhA, AlA, 0);
    if (1 < NK) { LOADB(BhB, BlB, 1); LOADA(AhB, AlB, 1); }
    int ks = 0;
    for (;;) {
      if (ks + 2 < NK) { LOADB(BhC, BlC, ks + 2); LOADA(AhC, AlC, ks + 2); }
      STEPK(AhA, AlA, BhA, BlA);
      if (++ks == NK) break;
      if (ks + 2 < NK) { LOADB(BhA, BlA, ks + 2); LOADA(AhA, AlA, ks + 2); }
      STEPK(AhB, AlB, BhB, BlB);
      if (++ks == NK) break;
      if (ks + 2 < NK) { LOADB(BhB, BlB, ks + 2); LOADA(AhB, AlB, ks + 2); }
      STEPK(AhC, AlC, BhC, BlC);
      if (++ks == NK) break;
    }
  }
#undef LOADB
#undef LOADA
#undef STEPK

  float lsA[MREP][4];
#pragma unroll
  for (int rep = 0; rep < MREP; ++rep) {
    const int rbase = (wm * MREP + rep) * 16 + lg * 4;
    float ls[4] = {0.f, 0.f, 0.f, 0.f};
    float gR[4], rcpom[4], onePc[4];
#pragma unroll
    for (int reg = 0; reg < 4; ++reg) {
      float cx2 = cA[rbase + reg];
      gR[reg] = gA[rbase + reg];
      rcpom[reg] = frcp(fmaxf(1.f - cx2, EPSF));
      onePc[reg] = 1.f + cx2;
    }
#pragma unroll
    for (int j = 0; j < NTW; ++j) {
      int o = (nt0 + j) * 16 + lm;
      float c1 = c1b[o], sh = shb[o], z2 = z2b[o];
#pragma unroll
      for (int reg = 0; reg < 4; ++reg) {
        float num = c1 * (gR[reg] * acc[rep][j][reg]) - onePc[reg] * sh;
        float yv = sinh_zasinh(num * rcpom[reg], z2);
        acc[rep][j][reg] = yv;
        ls[reg] += yv * yv;
      }
    }
#pragma unroll
    for (int mask = 1; mask < 16; mask <<= 1)
#pragma unroll
      for (int reg = 0; reg < 4; ++reg)
        ls[reg] += __shfl_xor(ls[reg], mask);
#pragma unroll
    for (int reg = 0; reg < 4; ++reg) lsA[rep][reg] = ls[reg];
    if constexpr (WN > 1) {
      if (lm == 0) {
#pragma unroll
        for (int reg = 0; reg < 4; ++reg)
          redw[wn * MT + rbase + reg] = ls[reg];
      }
    }
  }
  __syncthreads();

  float* tr = (float*)winbuf;
#pragma unroll
  for (int rep = 0; rep < MREP; ++rep) {
    const int rbase = (wm * MREP + rep) * 16 + lg * 4;
    float fs[4];
#pragma unroll
    for (int reg = 0; reg < 4; ++reg) {
      float s;
      if constexpr (WN > 1) {
        s = 0.f;
#pragma unroll
        for (int k2 = 0; k2 < WN; ++k2) s += redw[k2 * MT + rbase + reg];
      } else {
        s = lsA[rep][reg];
      }
      float inv = frcp(1.f + sqrtf(1.f + s));
      float ny = sqrtf(fmaxf(s * inv * inv, EPSF));
      fs[reg] = atanh_over(ny) * inv;
    }
#pragma unroll
    for (int j = 0; j < NTW; ++j) {
      int o = (nt0 + j) * 16 + lm;
#pragma unroll
      for (int reg = 0; reg < 4; ++reg)
        tr[o * TRS + rbase + reg] = fs[reg] * fmaxf(acc[rep][j][reg], 0.f);
    }
  }
  __syncthreads();

  const int y0p = y0 >> 1, x0p = x0 >> 1;
  if (tid < NPP * CG) {
    int cg = tid / NPP, p = tid - cg * NPP;
    int ppy = p / PW, ppx = p - ppy * PW;
    const float* base = tr + (ppy * 2) * TW + ppx * 2;
    float ss = 0.f;
#pragma unroll
    for (int j = 0; j < CPG; ++j) {
      int c = cg * CPG + j;
      const float* rp = base + c * TRS;
      float mv = fmaxf(fmaxf(rp[0], rp[1]), fmaxf(rp[TW], rp[TW + 1]));
      mout[((size_t)(b * COUT + c) * HO + y0p + ppy) * WO + x0p + ppx] = mv;
      ss += mv * mv;
    }
    pacc[cg * NPP + p] = ss;
  }
  __syncthreads();
  if (tid < NPP) {
    float ss = 0.f;
    for (int k2 = 0; k2 < CG; ++k2) ss += pacc[k2 * NPP + tid];
    int ppy = tid / PW, ppx = tid - (tid / PW) * PW;
    size_t pix = ((size_t)b * HO + y0p + ppy) * WO + x0p + ppx;
    s2out[pix] = ss;
    float n = sqrtf(fmaxf(ss, EPSF));
    fout[pix] = tanh_over(n);
  }
}

// ---------------- head: parallel Poincare FC --------------------------------
template <int NIN, int NOUT, bool POS, bool FUSEH, int NTP>
__global__ __launch_bounds__(256) void pfc_y_kernel(
    const float* __restrict__ x, const float* __restrict__ z,
    const float* __restrict__ r, const float* __restrict__ zn,
    float* __restrict__ ybuf, float* __restrict__ part,
    float* __restrict__ partpos, const float* __restrict__ pin,
    const float* __restrict__ pinpos) {
  constexpr int KCH = NIN / 4;
  const int b = blockIdx.y, tid = threadIdx.x;
  const int nt = gridDim.x;
  const int o = blockIdx.x * 64 + (tid & 63);
  const int kg = tid >> 6;
  __shared__ float xs[NIN];
  __shared__ float red[256];
  float cmb = 1.f;
  if constexpr (FUSEH) {
    float s = 0.f, sp = 0.f;
#pragma unroll
    for (int t = 0; t < NTP; ++t) {
      s += pin[(size_t)b * NTP + t];
      sp += pinpos[(size_t)b * NTP + t];
    }
    float inv = frcp(1.f + sqrtf(1.f + s));
    float ny = sqrtf(fmaxf(s, EPSF)) * inv;
    float fl = atanh_over(ny) * inv;
    float nw = fl * sqrtf(fmaxf(sp, EPSF));
    cmb = tanh_over(nw) * fl;
  }
  for (int i = tid; i < NIN; i += 256) {
    float v = x[(size_t)b * NIN + i];
    xs[i] = FUSEH ? cmb * fmaxf(v, 0.f) : v;
  }
  __syncthreads();
  float s = 0.f;
  for (int i = tid; i < NIN; i += 256) { float v = xs[i]; s += v * v; }
  red[tid] = s;
  __syncthreads();
  for (int st = 128; st > 0; st >>= 1) {
    if (tid < st) red[tid] += red[tid + st];
    __syncthreads();
  }
  const float cx2 = red[0];
  __syncthreads();
  float d = 0.f;
  if (o < NOUT) {
    const float* zp = z + (size_t)(kg * KCH) * NOUT + o;
    const float* xp = xs + kg * KCH;
    for (int k = 0; k < KCH; ++k) d = fmaf(xp[k], zp[(size_t)k * NOUT], d);
  }
  red[tid] = d;
  __syncthreads();
  if (tid < 64) {
    float dot = red[tid] + red[tid + 64] + red[tid + 128] + red[tid + 192];
    float y = 0.f;
    if (o < NOUT) {
      float znv = zn[o], rv = r[o];
      float onemc = fmaxf(1.f - cx2, EPSF);
      float num = 2.f * (dot / znv) * coshf(2.f * rv) - (1.f + cx2) * sinhf(2.f * rv);
      y = sinh_zasinh(num * frcp(onemc), 2.f * znv);
      ybuf[(size_t)b * NOUT + o] = y;
    }
    float ls = y * y;
    float lp = POS ? (fmaxf(y, 0.f) * fmaxf(y, 0.f)) : 0.f;
#pragma unroll
    for (int mask = 1; mask < 64; mask <<= 1) {
      ls += __shfl_xor(ls, mask);
      if (POS) lp += __shfl_xor(lp, mask);
    }
    if (tid == 0) {
      part[(size_t)b * nt + blockIdx.x] = ls;
      if (POS) partpos[(size_t)b * nt + blockIdx.x] = lp;
    }
  }
}

template <int NOUT, int NT>
__global__ __launch_bounds__(256) void pfc_fin_kernel(
    const float* __restrict__ ybuf, const float* __restrict__ part,
    float* __restrict__ out) {
  const int b = blockIdx.x, tid = threadIdx.x;
  float s = 0.f;
#pragma unroll
  for (int t = 0; t < NT; ++t) s += part[(size_t)b * NT + t];
  float inv = frcp(1.f + sqrtf(1.f + s));
  for (int o = tid; o < NOUT; o += 256)
    out[(size_t)b * NOUT + o] = ybuf[(size_t)b * NOUT + o] * inv;
}

// ---------------------------------------------------------------------------
static inline double beta_fn(double a, double b) {
  return std::exp(std::lgamma(a) + std::lgamma(b) - std::lgamma(a + b));
}

extern "C" void kernel_launch(void* const* d_in, const int* in_sizes, int n_in,
                              void* d_out, int out_size, void* d_ws, size_t ws_size,
                              hipStream_t stream) {
  const float* x   = (const float*)d_in[0];
  const float* z1  = (const float*)d_in[1];
  const float* b1  = (const float*)d_in[2];
  const float* z2  = (const float*)d_in[3];
  const float* b2  = (const float*)d_in[4];
  const float* z3  = (const float*)d_in[5];
  const float* b3  = (const float*)d_in[6];
  const float* z4  = (const float*)d_in[7];
  const float* b4  = (const float*)d_in[8];
  const float* zf1 = (const float*)d_in[9];
  const float* bf1 = (const float*)d_in[10];
  const float* zf2 = (const float*)d_in[11];
  const float* bf2 = (const float*)d_in[12];
  float* outp = (float*)d_out;

  float* ws    = (float*)d_ws;
  float* zn    = ws;                        // 2048
  float* flat  = ws + 2048;                 // 5632
  float* yb1   = ws + 7680;                 // 8192 (FC1 raw y)
  float* yb2   = ws + 15872;                // 16000
  float* hp1   = ws + 31872;                // 128
  float* hpp1  = ws + 32000;                // 128
  float* hp2   = ws + 32128;                // 256
  float* part  = ws + 32768;                // 32768 (znorm partials 16x2048)
  float* m1    = ws + 65536;                // 2,097,152
  float* m2    = m1 + 2097152;              // 1,048,576
  float* m3    = m2 + 1048576;              // 524,288
  float* m4    = m3 + 524288;               // 131,072
  float* s1b   = m4 + 131072;               // 65,536
  float* s2bf  = s1b + 65536;               // 16,384
  float* s3b   = s2bf + 16384;              // 4,096
  float* s4b   = s3b + 4096;                // 1,024
  float* f1    = s4b + 1024;                // 65,536
  float* f2    = f1 + 65536;                // 16,384
  float* f3    = f2 + 16384;                // 4,096
  float* f4    = f3 + 4096;                 // 1,024
  unsigned short* zfu = (unsigned short*)(f4 + 1024);
  unsigned short* zf1h = zfu;               //   3,072
  unsigned short* zf1l = zfu + 3072;
  unsigned short* zf2h = zfu + 6144;        //  51,200
  unsigned short* zf2l = zfu + 57344;
  unsigned short* zf3h = zfu + 108544;      // 401,408
  unsigned short* zf3l = zfu + 509952;
  unsigned short* zf4h = zfu + 911360;      // 147,456
  unsigned short* zf4l = zfu + 1058816;     // ends 1,206,272 ushorts

  const float s1  = (float)(beta_fn(27.0 / 2.0, 0.5) / beta_fn(3.0 / 2.0, 0.5));
  const float s2c = (float)(beta_fn(800.0 / 2.0, 0.5) / beta_fn(32.0 / 2.0, 0.5));
  const float s3  = (float)(beta_fn(3136.0 / 2.0, 0.5) / beta_fn(64.0 / 2.0, 0.5));
  const float s4  = (float)(beta_fn(1152.0 / 2.0, 0.5) / beta_fn(128.0 / 2.0, 0.5));

  // prep
  znorm_all_kernel<<<dim3(30, 16), 256, 0, stream>>>(z1, z2, z3, z4, zf1, zf2, part);
  znorm_fin_kernel<<<8, 256, 0, stream>>>(part, zn);
  zfprep_all_kernel<<<2356, 256, 0, stream>>>(z1, z2, z3, z4, zf1h, zf1l,
                                              zf2h, zf2l, zf3h, zf3l, zf4h, zf4l);

  // ---- layer 1: x (16,3,128,128) -> m1 (16,32,64,64)  [logmap fused]
  hconv_mfma<3, 3, 12, 3, 1, 32, 128, 128, 8, 8, 4, 1, 1, true>
      <<<4096, 256, 0, stream>>>(x, nullptr, zf1h, zf1l, b1, zn + 0, m1, s1b, f1, s1);

  // ---- layer 2: m1 -> m2 (16,64,32,32)
  hconv_mfma<32, 5, 25, 5, 2, 64, 64, 64, 8, 8, 2, 2, 2, false>
      <<<1024, 256, 0, stream>>>(m1, s1b, zf2h, zf2l, b2, zn + 32, m2, s2bf, f2, s2c);

  // ---- layer 3: m2 -> m3 (16,128,16,16)
  hconv_mfma<64, 6, 49, 7, 3, 128, 32, 32, 4, 8, 1, 2, 4, false>
      <<<512, 256, 0, stream>>>(m2, s2bf, zf3h, zf3l, b3, zn + 96, m3, s3b, f3, s3);

  // ---- layer 4: m3 -> m4 (16,128,8,8)
  hconv_mfma<128, 7, 9, 3, 1, 128, 16, 16, 2, 8, 1, 1, 8, false>
      <<<256, 512, 0, stream>>>(m3, s3b, zf4h, zf4l, b4, zn + 224, m4, s4b, f4, s4);

  // ---- features: merged weighted avgpools -> flat (16,352)
  wavgpool_all_kernel<<<dim3(352, 16), 256, 0, stream>>>(
      m1, m2, m3, m4, f1, f2, f3, f4, flat);

  // ---- head
  pfc_y_kernel<352, 512, true, false, 0><<<dim3(8, 16), 256, 0, stream>>>(
      flat, zf1, bf1, zn + 352, yb1, hp1, hpp1, nullptr, nullptr);
  pfc_y_kernel<512, 1000, false, true, 8><<<dim3(16, 16), 256, 0, stream>>>(
      yb1, zf2, bf2, zn + 864, yb2, hp2, nullptr, hp1, hpp1);
  pfc_fin_kernel<1000, 16><<<16, 256, 0, stream>>>(yb2, hp2, outp);

  (void)in_sizes; (void)n_in; (void)out_size; (void)ws_size;
}

// Round 16
// 169.215 us; speedup vs baseline: 1.1970x; 1.1970x over previous
//
#include <hip/hip_runtime.h>
#include <cmath>

// ---------------------------------------------------------------------------
// Hyperbolic MS-CNN (Poincare ball, c=1) — round 16 (revert to r13 best +
// znorm_fin folded into zfprep_all).
//  * MFMA convs (split bf16 hi/lo, 3 MFMAs) + fused epilogue + MREP.
//  * conv1 fuses logmap0; merged wavgpool; hrelu fused into FC2 head.
// ---------------------------------------------------------------------------

#define EPSF 1e-15f
#define ATANH_CAP 0.9999999f  // 1 - 1e-7

typedef __attribute__((ext_vector_type(8))) short short8;
typedef __attribute__((ext_vector_type(4))) float f32x4;

__device__ inline unsigned rne16(float f) {
  unsigned u = __float_as_uint(f);
  return (u + 0x7FFFu + ((u >> 16) & 1u)) >> 16;
}
__device__ inline float fexp2(float x) { return __builtin_amdgcn_exp2f(x); }
__device__ inline float flog2(float x) { return __builtin_amdgcn_logf(x); }
__device__ inline float frcp(float x) { return __builtin_amdgcn_rcpf(x); }

__device__ inline float atanh_over(float n) {
  float nc = fminf(n, ATANH_CAP);
  float f = 0.34657359f * flog2((1.f + nc) * frcp(1.f - nc)) * frcp(n);
  float s = 1.f + 0.33333333f * n * n;
  return (n < 0.004f) ? s : f;
}
__device__ inline float tanh_over(float n) {
  float p2 = fexp2(2.885390082f * n);  // e^{2n}
  float f = (1.f - 2.f * frcp(p2 + 1.f)) * frcp(n);
  float s = 1.f - 0.33333333f * n * n;
  return (n < 0.004f) ? s : f;
}
__device__ inline float sinh_zasinh(float q, float twozn) {
  float aq = fabsf(q);
  float t = aq + sqrtf(fmaf(aq, aq, 1.f));
  float p = fexp2(twozn * flog2(t));
  float y = 0.5f * (p - frcp(p));
  return copysignf(y, q);
}

// ---------------- merged z column norms, stage 1 ----------------------------
__global__ __launch_bounds__(256) void znorm_all_kernel(
    const float* __restrict__ z1, const float* __restrict__ z2,
    const float* __restrict__ z3, const float* __restrict__ z4,
    const float* __restrict__ zf1, const float* __restrict__ zf2,
    float* __restrict__ part) {
  const int bx = blockIdx.x;
  const float* z; int K, Nout, coff, lb;
  if (bx < 1)       { z = z1;  K = 27;   Nout = 32;   coff = 0;   lb = bx; }
  else if (bx < 2)  { z = z2;  K = 800;  Nout = 64;   coff = 32;  lb = bx - 1; }
  else if (bx < 4)  { z = z3;  K = 3136; Nout = 128;  coff = 96;  lb = bx - 2; }
  else if (bx < 6)  { z = z4;  K = 1152; Nout = 128;  coff = 224; lb = bx - 4; }
  else if (bx < 14) { z = zf1; K = 352;  Nout = 512;  coff = 352; lb = bx - 6; }
  else              { z = zf2; K = 512;  Nout = 1000; coff = 864; lb = bx - 14; }
  const int tid = threadIdx.x;
  const int col = lb * 64 + (tid & 63);
  const int kg = (blockIdx.y << 2) + (tid >> 6);
  float s = 0.f;
  if (col < Nout)
    for (int k = kg; k < K; k += 64) {
      float v = z[(size_t)k * Nout + col];
      s += v * v;
    }
  __shared__ float red[256];
  red[tid] = s;
  __syncthreads();
  if (tid < 64 && col < Nout) {
    float t = red[tid] + red[tid + 64] + red[tid + 128] + red[tid + 192];
    part[(size_t)blockIdx.y * 2048 + coff + col] = t;
  }
}

// ---------------- z -> MFMA-fragment-ordered hi/lo bf16 (merged) ------------
template <int CIN, int CSH, int TAPS, int KK, int COUT>
__device__ inline void zfprep_body(int blk, const float* __restrict__ z,
                                   unsigned short* __restrict__ zh,
                                   unsigned short* __restrict__ zl) {
  constexpr int CPAD = 1 << CSH;
  constexpr int KP = TAPS * CPAD;
  constexpr int NT = COUT / 16;
  int t = blk * 256 + threadIdx.x;
  if (t >= KP * COUT) return;
  int k = t / COUT, n = t - k * COUT;
  int ks = k >> 5, lg = (k >> 3) & 3, i = k & 7;
  int nt = n >> 4, lm = n & 15;
  size_t e = ((size_t)(ks * NT + nt) * 64 + lg * 16 + lm) * 8 + i;
  int tap = k >> CSH, c = k & (CPAD - 1);
  float val = (c < CIN && tap < KK) ? z[(size_t)(c * KK + tap) * COUT + n] : 0.f;
  unsigned hi = rne16(val);
  float hif = __uint_as_float(hi << 16);
  unsigned lo = rne16(val - hif);
  zh[e] = (unsigned short)hi;
  zl[e] = (unsigned short)lo;
}
// grid 2364: [0,12) z1 | [12,212) z2 | [212,1780) z3 | [1780,2356) z4 |
//            [2356,2364) znorm finish (independent of zfprep outputs)
__global__ __launch_bounds__(256) void zfprep_all_kernel(
    const float* __restrict__ z1, const float* __restrict__ z2,
    const float* __restrict__ z3, const float* __restrict__ z4,
    unsigned short* __restrict__ zf1h, unsigned short* __restrict__ zf1l,
    unsigned short* __restrict__ zf2h, unsigned short* __restrict__ zf2l,
    unsigned short* __restrict__ zf3h, unsigned short* __restrict__ zf3l,
    unsigned short* __restrict__ zf4h, unsigned short* __restrict__ zf4l,
    const float* __restrict__ part, float* __restrict__ zn) {
  const int bx = blockIdx.x;
  if (bx < 12)        zfprep_body<3, 3, 12, 9, 32>(bx, z1, zf1h, zf1l);
  else if (bx < 212)  zfprep_body<32, 5, 25, 25, 64>(bx - 12, z2, zf2h, zf2l);
  else if (bx < 1780) zfprep_body<64, 6, 49, 49, 128>(bx - 212, z3, zf3h, zf3l);
  else if (bx < 2356) zfprep_body<128, 7, 9, 9, 128>(bx - 1780, z4, zf4h, zf4l);
  else {
    int c = (bx - 2356) * 256 + threadIdx.x;
    float s = 0.f;
#pragma unroll
    for (int rr = 0; rr < 16; ++rr) s += part[rr * 2048 + c];
    zn[c] = sqrtf(fmaxf(s, EPSF));
  }
}

// ---------------- merged weighted spatial means ------------------------------
__global__ __launch_bounds__(256) void wavgpool_all_kernel(
    const float* __restrict__ m1, const float* __restrict__ m2,
    const float* __restrict__ m3, const float* __restrict__ m4,
    const float* __restrict__ f1, const float* __restrict__ f2,
    const float* __restrict__ f3, const float* __restrict__ f4,
    float* __restrict__ flat) {
  const int c = blockIdx.x, b = blockIdx.y, tid = threadIdx.x;
  const float* m; const float* f; int HW, C, cl;
  if (c < 32)       { m = m1; f = f1; HW = 4096; C = 32;  cl = c; }
  else if (c < 96)  { m = m2; f = f2; HW = 1024; C = 64;  cl = c - 32; }
  else if (c < 224) { m = m3; f = f3; HW = 256;  C = 128; cl = c - 96; }
  else              { m = m4; f = f4; HW = 64;   C = 128; cl = c - 224; }
  const float* p = m + ((size_t)b * C + cl) * HW;
  const float* q = f + (size_t)b * HW;
  float s = 0.f;
  for (int i = tid; i < HW; i += 256) s += p[i] * q[i];
  __shared__ float red[256];
  red[tid] = s; __syncthreads();
  for (int st = 128; st > 0; st >>= 1) {
    if (tid < st) red[tid] += red[tid + st];
    __syncthreads();
  }
  if (tid == 0) flat[(size_t)b * 352 + c] = red[0] / (float)HW;
}

// ---------------- MFMA fused hconv + hrelu-tangent + maxpool + maps ---------
template <int CIN, int CSH, int TAPS, int K, int PAD, int COUT, int H, int W,
          int TH, int TW, int WM, int MREP, int WN, bool FLOG>
__global__ __launch_bounds__(WM * WN * 64) void hconv_mfma(
    const float* __restrict__ vin, const float* __restrict__ s2map,
    const unsigned short* __restrict__ zfh,
    const unsigned short* __restrict__ zfl,
    const float* __restrict__ r, const float* __restrict__ zn,
    float* __restrict__ mout, float* __restrict__ s2out,
    float* __restrict__ fout, float scale) {
  constexpr int NTHR = WM * WN * 64;
  constexpr int CPAD = 1 << CSH;
  constexpr int KK = K * K;
  constexpr int MT = WM * MREP * 16;
  static_assert(MT == TH * TW, "tile rows mismatch");
  constexpr int NT = COUT / 16;
  constexpr int NTW = NT / WN;
  static_assert(NTW * WN == NT, "");
  constexpr int NK = TAPS * CPAD / 32;
  static_assert(NK * 32 == TAPS * CPAD, "K-step misalign");
  constexpr int SY = TH + K - 1, SX = TW + K - 1;
  constexpr int NPOS = SY * SX;
  constexpr int RWU = (CPAD >= 32) ? (CPAD + 8) : CPAD;
  constexpr int CGR = CPAD / 8;
  constexpr int TRS = MT + 4;
  constexpr int WINU = NPOS * RWU;
  constexpr int TRU = 2 * COUT * TRS;
  constexpr int SHU = (2 * WINU > TRU) ? 2 * WINU : TRU;
  constexpr int HO = H / 2, WO = W / 2;
  constexpr int PH = TH / 2, PW = TW / 2, NPP = PH * PW;
  constexpr int CG0 = NTHR / NPP;
  constexpr int CG = (CG0 < COUT) ? CG0 : COUT;
  constexpr int CPG = COUT / CG;
  static_assert(CPG * CG == COUT, "pool split");
  constexpr int SENT = 1 << 30;

  __shared__ __align__(16) unsigned short winbuf[SHU];
  __shared__ float s2w[NPOS];
  __shared__ float gA[MT], cA[MT];
  __shared__ float c1b[COUT], shb[COUT], z2b[COUT];
  __shared__ float redw[(WN > 1) ? WN * MT : 1];
  __shared__ float pacc[NTHR];
  __shared__ int stab[NK * 4];
  unsigned short* winh = winbuf;
  unsigned short* winl = winbuf + WINU;

  const int tid = threadIdx.x;
  int bid = blockIdx.x;
  constexpr int TXC = W / TW, TYC = H / TH;
  const int tx = bid % TXC; bid /= TXC;
  const int ty = bid % TYC; const int b = bid / TYC;
  const int y0 = ty * TH, x0 = tx * TW;

  if (tid < COUT) {
    float rv = r[tid];
    float znv = zn[tid];
    float ch = coshf(2.f * rv), sh = sinhf(2.f * rv);
    c1b[tid] = 2.f * ch / znv;
    shb[tid] = sh;
    z2b[tid] = 2.f * znv;
  }
  for (int i = tid; i < NK * 4; i += NTHR) {
    int ks = i >> 2, lg2 = i & 3;
    int kbase = ks * 32 + lg2 * 8;
    int tap = kbase >> CSH, c0 = kbase & (CPAD - 1);
    int v;
    if (TAPS != KK && tap >= KK) {
      v = SENT;
    } else {
      int iy = tap / K, ix = tap - (tap / K) * K;
      v = (iy * SX + ix) * RWU + c0;
    }
    stab[i] = v;
  }
  const float* vb = vin + (size_t)b * CIN * H * W;
  if constexpr (FLOG) {
    static_assert(CIN == 3 && CPAD == 8, "FLOG expects CIN=3");
    for (int pos = tid; pos < NPOS; pos += NTHR) {
      int sy = pos / SX, sx = pos - sy * SX;
      int gy = y0 + sy - PAD, gx = x0 + sx - PAD;
      bool inb = (gy >= 0 && gy < H && gx >= 0 && gx < W);
      float v0 = 0.f, v1 = 0.f, v2 = 0.f;
      if (inb) {
        const float* gp = vb + gy * W + gx;
        v0 = gp[0];
        v1 = gp[(size_t)H * W];
        v2 = gp[(size_t)2 * H * W];
      }
      float ssr = v0 * v0 + v1 * v1 + v2 * v2;
      float n = sqrtf(fmaxf(ssr, EPSF));
      float f = atanh_over(n);
      s2w[pos] = f * f * ssr;
      float vals[8] = {f * v0, f * v1, f * v2, 0.f, 0.f, 0.f, 0.f, 0.f};
      short8 hv, lv;
#pragma unroll
      for (int j = 0; j < 8; ++j) {
        unsigned hi = rne16(vals[j]);
        float hif = __uint_as_float(hi << 16);
        unsigned lo = rne16(vals[j] - hif);
        hv[j] = (short)hi;
        lv[j] = (short)lo;
      }
      *(short8*)(winh + pos * RWU) = hv;
      *(short8*)(winl + pos * RWU) = lv;
    }
  } else {
    for (int idx = tid; idx < CGR * NPOS; idx += NTHR) {
      int pos = idx / CGR;
      int cg = idx - pos * CGR;
      int sy = pos / SX, sx = pos - sy * SX;
      int gy = y0 + sy - PAD, gx = x0 + sx - PAD;
      bool inb = (gy >= 0 && gy < H && gx >= 0 && gx < W);
      const float* gp = vb + (size_t)(cg * 8) * H * W + gy * W + gx;
      short8 hv, lv;
#pragma unroll
      for (int j = 0; j < 8; ++j) {
        float val = 0.f;
        if constexpr (CIN == CPAD) {
          if (inb) val = gp[(size_t)j * H * W];
        } else {
          if (inb && (cg * 8 + j) < CIN) val = gp[(size_t)j * H * W];
        }
        unsigned hi = rne16(val);
        float hif = __uint_as_float(hi << 16);
        unsigned lo = rne16(val - hif);
        hv[j] = (short)hi;
        lv[j] = (short)lo;
      }
      *(short8*)(winh + pos * RWU + cg * 8) = hv;
      *(short8*)(winl + pos * RWU + cg * 8) = lv;
    }
    const float* s2bp = s2map + (size_t)b * H * W;
    for (int i = tid; i < NPOS; i += NTHR) {
      int sy = i / SX, sx = i - sy * SX;
      int gy = y0 + sy - PAD, gx = x0 + sx - PAD;
      s2w[i] = (gy >= 0 && gy < H && gx >= 0 && gx < W) ? s2bp[gy * W + gx] : 0.f;
    }
  }
  __syncthreads();

  if (tid < MT) {
    int py = tid / TW, px = tid - (tid / TW) * TW;
    float s = 0.f;
    for (int iy = 0; iy < K; ++iy)
      for (int ix = 0; ix < K; ++ix)
        s += s2w[(py + iy) * SX + (px + ix)];
    float n = sqrtf(fmaxf(scale * scale * s, EPSF));
    float th = n * tanh_over(n);
    gA[tid] = th * scale * frcp(n);
    cA[tid] = th * th;
  }
  __syncthreads();

  const int w = __builtin_amdgcn_readfirstlane(tid >> 6);
  const int wm = w % WM, wn = w / WM;
  const int lane = tid & 63, lm = lane & 15, lg = lane >> 4;
  const int nt0 = wn * NTW;

  int abase[MREP];
#pragma unroll
  for (int rep = 0; rep < MREP; ++rep) {
    int m = (wm * MREP + rep) * 16 + lm;
    int py = m / TW, px = m - (m / TW) * TW;
    abase[rep] = (py * SX + px) * RWU;
  }

  f32x4 acc[MREP][NTW];
#pragma unroll
  for (int rep = 0; rep < MREP; ++rep)
#pragma unroll
    for (int j = 0; j < NTW; ++j) acc[rep][j] = (f32x4){0.f, 0.f, 0.f, 0.f};

  const unsigned short* bph = zfh + (size_t)nt0 * 512 + lane * 8;
  const unsigned short* bpl = zfl + (size_t)nt0 * 512 + lane * 8;
  constexpr size_t BSTEP = (size_t)NT * 512;

#define LOADB(BH, BL, KS)                                             \
  do {                                                                \
    const unsigned short* ph_ = bph + (size_t)(KS)*BSTEP;             \
    const unsigned short* pl_ = bpl + (size_t)(KS)*BSTEP;             \
    _Pragma("unroll") for (int j_ = 0; j_ < NTW; ++j_) {              \
      BH[j_] = *(const uint4*)(ph_ + j_ * 512);                       \
      BL[j_] = *(const uint4*)(pl_ + j_ * 512);                       \
    }                                                                 \
  } while (0)

#define LOADA(AH, AL, KS)                                             \
  do {                                                                \
    const int so_ = stab[(KS)*4 + lg];                                \
    bool valid_ = true;                                               \
    if constexpr (TAPS != KK) valid_ = (so_ < SENT);                  \
    _Pragma("unroll") for (int r_ = 0; r_ < MREP; ++r_) {             \
      if (valid_) {                                                   \
        const int lofs_ = abase[r_] + so_;                            \
        AH[r_] = *(const short8*)(winh + lofs_);                      \
        AL[r_] = *(const short8*)(winl + lofs_);                      \
      } else {                                                        \
        AH[r_] = (short8){};                                          \
        AL[r_] = (short8){};                                          \
      }                                                               \
    }                                                                 \
  } while (0)

#define STEPK(AH, AL, BH, BL)                                         \
  do {                                                                \
    _Pragma("unroll") for (int rep_ = 0; rep_ < MREP; ++rep_) {       \
      _Pragma("unroll") for (int j_ = 0; j_ < NTW; ++j_) {            \
        short8 bhv_ = __builtin_bit_cast(short8, BH[j_]);             \
        short8 blv_ = __builtin_bit_cast(short8, BL[j_]);             \
        acc[rep_][j_] = __builtin_amdgcn_mfma_f32_16x16x32_bf16(      \
            AH[rep_], bhv_, acc[rep_][j_], 0, 0, 0);                  \
        acc[rep_][j_] = __builtin_amdgcn_mfma_f32_16x16x32_bf16(      \
            AH[rep_], blv_, acc[rep_][j_], 0, 0, 0);                  \
        acc[rep_][j_] = __builtin_amdgcn_mfma_f32_16x16x32_bf16(      \
            AL[rep_], bhv_, acc[rep_][j_], 0, 0, 0);                  \
      }                                                               \
    }                                                                 \
  } while (0)

  {
    uint4 BhA[NTW], BlA[NTW], BhB[NTW], BlB[NTW];
    short8 AhA[MREP], AlA[MREP], AhB[MREP], AlB[MREP];
    LOADB(BhA, BlA, 0);
    LOADA(AhA, AlA, 0);
    int ks = 0;
    for (;;) {
      if (ks + 1 < NK) { LOADB(BhB, BlB, ks + 1); LOADA(AhB, AlB, ks + 1); }
      STEPK(AhA, AlA, BhA, BlA);
      if (++ks == NK) break;
      if (ks + 1 < NK) { LOADB(BhA, BlA, ks + 1); LOADA(AhA, AlA, ks + 1); }
      STEPK(AhB, AlB, BhB, BlB);
      if (++ks == NK) break;
    }
  }
#undef LOADB
#undef LOADA
#undef STEPK

  float lsA[MREP][4];
#pragma unroll
  for (int rep = 0; rep < MREP; ++rep) {
    const int rbase = (wm * MREP + rep) * 16 + lg * 4;
    float ls[4] = {0.f, 0.f, 0.f, 0.f};
    float gR[4], rcpom[4], onePc[4];
#pragma unroll
    for (int reg = 0; reg < 4; ++reg) {
      float cx2 = cA[rbase + reg];
      gR[reg] = gA[rbase + reg];
      rcpom[reg] = frcp(fmaxf(1.f - cx2, EPSF));
      onePc[reg] = 1.f + cx2;
    }
#pragma unroll
    for (int j = 0; j < NTW; ++j) {
      int o = (nt0 + j) * 16 + lm;
      float c1 = c1b[o], sh = shb[o], z2 = z2b[o];
#pragma unroll
      for (int reg = 0; reg < 4; ++reg) {
        float num = c1 * (gR[reg] * acc[rep][j][reg]) - onePc[reg] * sh;
        float yv = sinh_zasinh(num * rcpom[reg], z2);
        acc[rep][j][reg] = yv;
        ls[reg] += yv * yv;
      }
    }
#pragma unroll
    for (int mask = 1; mask < 16; mask <<= 1)
#pragma unroll
      for (int reg = 0; reg < 4; ++reg)
        ls[reg] += __shfl_xor(ls[reg], mask);
#pragma unroll
    for (int reg = 0; reg < 4; ++reg) lsA[rep][reg] = ls[reg];
    if constexpr (WN > 1) {
      if (lm == 0) {
#pragma unroll
        for (int reg = 0; reg < 4; ++reg)
          redw[wn * MT + rbase + reg] = ls[reg];
      }
    }
  }
  __syncthreads();

  float* tr = (float*)winbuf;
#pragma unroll
  for (int rep = 0; rep < MREP; ++rep) {
    const int rbase = (wm * MREP + rep) * 16 + lg * 4;
    float fs[4];
#pragma unroll
    for (int reg = 0; reg < 4; ++reg) {
      float s;
      if constexpr (WN > 1) {
        s = 0.f;
#pragma unroll
        for (int k2 = 0; k2 < WN; ++k2) s += redw[k2 * MT + rbase + reg];
      } else {
        s = lsA[rep][reg];
      }
      float inv = frcp(1.f + sqrtf(1.f + s));
      float ny = sqrtf(fmaxf(s * inv * inv, EPSF));
      fs[reg] = atanh_over(ny) * inv;
    }
#pragma unroll
    for (int j = 0; j < NTW; ++j) {
      int o = (nt0 + j) * 16 + lm;
#pragma unroll
      for (int reg = 0; reg < 4; ++reg)
        tr[o * TRS + rbase + reg] = fs[reg] * fmaxf(acc[rep][j][reg], 0.f);
    }
  }
  __syncthreads();

  const int y0p = y0 >> 1, x0p = x0 >> 1;
  if (tid < NPP * CG) {
    int cg = tid / NPP, p = tid - cg * NPP;
    int ppy = p / PW, ppx = p - ppy * PW;
    const float* base = tr + (ppy * 2) * TW + ppx * 2;
    float ss = 0.f;
#pragma unroll
    for (int j = 0; j < CPG; ++j) {
      int c = cg * CPG + j;
      const float* rp = base + c * TRS;
      float mv = fmaxf(fmaxf(rp[0], rp[1]), fmaxf(rp[TW], rp[TW + 1]));
      mout[((size_t)(b * COUT + c) * HO + y0p + ppy) * WO + x0p + ppx] = mv;
      ss += mv * mv;
    }
    pacc[cg * NPP + p] = ss;
  }
  __syncthreads();
  if (tid < NPP) {
    float ss = 0.f;
    for (int k2 = 0; k2 < CG; ++k2) ss += pacc[k2 * NPP + tid];
    int ppy = tid / PW, ppx = tid - (tid / PW) * PW;
    size_t pix = ((size_t)b * HO + y0p + ppy) * WO + x0p + ppx;
    s2out[pix] = ss;
    float n = sqrtf(fmaxf(ss, EPSF));
    fout[pix] = tanh_over(n);
  }
}

// ---------------- head: parallel Poincare FC --------------------------------
template <int NIN, int NOUT, bool POS, bool FUSEH, int NTP>
__global__ __launch_bounds__(256) void pfc_y_kernel(
    const float* __restrict__ x, const float* __restrict__ z,
    const float* __restrict__ r, const float* __restrict__ zn,
    float* __restrict__ ybuf, float* __restrict__ part,
    float* __restrict__ partpos, const float* __restrict__ pin,
    const float* __restrict__ pinpos) {
  constexpr int KCH = NIN / 4;
  const int b = blockIdx.y, tid = threadIdx.x;
  const int nt = gridDim.x;
  const int o = blockIdx.x * 64 + (tid & 63);
  const int kg = tid >> 6;
  __shared__ float xs[NIN];
  __shared__ float red[256];
  float cmb = 1.f;
  if constexpr (FUSEH) {
    float s = 0.f, sp = 0.f;
#pragma unroll
    for (int t = 0; t < NTP; ++t) {
      s += pin[(size_t)b * NTP + t];
      sp += pinpos[(size_t)b * NTP + t];
    }
    float inv = frcp(1.f + sqrtf(1.f + s));
    float ny = sqrtf(fmaxf(s, EPSF)) * inv;
    float fl = atanh_over(ny) * inv;
    float nw = fl * sqrtf(fmaxf(sp, EPSF));
    cmb = tanh_over(nw) * fl;
  }
  for (int i = tid; i < NIN; i += 256) {
    float v = x[(size_t)b * NIN + i];
    xs[i] = FUSEH ? cmb * fmaxf(v, 0.f) : v;
  }
  __syncthreads();
  float s = 0.f;
  for (int i = tid; i < NIN; i += 256) { float v = xs[i]; s += v * v; }
  red[tid] = s;
  __syncthreads();
  for (int st = 128; st > 0; st >>= 1) {
    if (tid < st) red[tid] += red[tid + st];
    __syncthreads();
  }
  const float cx2 = red[0];
  __syncthreads();
  float d = 0.f;
  if (o < NOUT) {
    const float* zp = z + (size_t)(kg * KCH) * NOUT + o;
    const float* xp = xs + kg * KCH;
    for (int k = 0; k < KCH; ++k) d = fmaf(xp[k], zp[(size_t)k * NOUT], d);
  }
  red[tid] = d;
  __syncthreads();
  if (tid < 64) {
    float dot = red[tid] + red[tid + 64] + red[tid + 128] + red[tid + 192];
    float y = 0.f;
    if (o < NOUT) {
      float znv = zn[o], rv = r[o];
      float onemc = fmaxf(1.f - cx2, EPSF);
      float num = 2.f * (dot / znv) * coshf(2.f * rv) - (1.f + cx2) * sinhf(2.f * rv);
      y = sinh_zasinh(num * frcp(onemc), 2.f * znv);
      ybuf[(size_t)b * NOUT + o] = y;
    }
    float ls = y * y;
    float lp = POS ? (fmaxf(y, 0.f) * fmaxf(y, 0.f)) : 0.f;
#pragma unroll
    for (int mask = 1; mask < 64; mask <<= 1) {
      ls += __shfl_xor(ls, mask);
      if (POS) lp += __shfl_xor(lp, mask);
    }
    if (tid == 0) {
      part[(size_t)b * nt + blockIdx.x] = ls;
      if (POS) partpos[(size_t)b * nt + blockIdx.x] = lp;
    }
  }
}

template <int NOUT, int NT>
__global__ __launch_bounds__(256) void pfc_fin_kernel(
    const float* __restrict__ ybuf, const float* __restrict__ part,
    float* __restrict__ out) {
  const int b = blockIdx.x, tid = threadIdx.x;
  float s = 0.f;
#pragma unroll
  for (int t = 0; t < NT; ++t) s += part[(size_t)b * NT + t];
  float inv = frcp(1.f + sqrtf(1.f + s));
  for (int o = tid; o < NOUT; o += 256)
    out[(size_t)b * NOUT + o] = ybuf[(size_t)b * NOUT + o] * inv;
}

// ---------------------------------------------------------------------------
static inline double beta_fn(double a, double b) {
  return std::exp(std::lgamma(a) + std::lgamma(b) - std::lgamma(a + b));
}

extern "C" void kernel_launch(void* const* d_in, const int* in_sizes, int n_in,
                              void* d_out, int out_size, void* d_ws, size_t ws_size,
                              hipStream_t stream) {
  const float* x   = (const float*)d_in[0];
  const float* z1  = (const float*)d_in[1];
  const float* b1  = (const float*)d_in[2];
  const float* z2  = (const float*)d_in[3];
  const float* b2  = (const float*)d_in[4];
  const float* z3  = (const float*)d_in[5];
  const float* b3  = (const float*)d_in[6];
  const float* z4  = (const float*)d_in[7];
  const float* b4  = (const float*)d_in[8];
  const float* zf1 = (const float*)d_in[9];
  const float* bf1 = (const float*)d_in[10];
  const float* zf2 = (const float*)d_in[11];
  const float* bf2 = (const float*)d_in[12];
  float* outp = (float*)d_out;

  float* ws    = (float*)d_ws;
  float* zn    = ws;                        // 2048
  float* flat  = ws + 2048;                 // 5632
  float* yb1   = ws + 7680;                 // 8192 (FC1 raw y)
  float* yb2   = ws + 15872;                // 16000
  float* hp1   = ws + 31872;                // 128
  float* hpp1  = ws + 32000;                // 128
  float* hp2   = ws + 32128;                // 256
  float* part  = ws + 32768;                // 32768 (znorm partials 16x2048)
  float* m1    = ws + 65536;                // 2,097,152
  float* m2    = m1 + 2097152;              // 1,048,576
  float* m3    = m2 + 1048576;              // 524,288
  float* m4    = m3 + 524288;               // 131,072
  float* s1b   = m4 + 131072;               // 65,536
  float* s2bf  = s1b + 65536;               // 16,384
  float* s3b   = s2bf + 16384;              // 4,096
  float* s4b   = s3b + 4096;                // 1,024
  float* f1    = s4b + 1024;                // 65,536
  float* f2    = f1 + 65536;                // 16,384
  float* f3    = f2 + 16384;                // 4,096
  float* f4    = f3 + 4096;                 // 1,024
  unsigned short* zfu = (unsigned short*)(f4 + 1024);
  unsigned short* zf1h = zfu;               //   3,072
  unsigned short* zf1l = zfu + 3072;
  unsigned short* zf2h = zfu + 6144;        //  51,200
  unsigned short* zf2l = zfu + 57344;
  unsigned short* zf3h = zfu + 108544;      // 401,408
  unsigned short* zf3l = zfu + 509952;
  unsigned short* zf4h = zfu + 911360;      // 147,456
  unsigned short* zf4l = zfu + 1058816;     // ends 1,206,272 ushorts

  const float s1  = (float)(beta_fn(27.0 / 2.0, 0.5) / beta_fn(3.0 / 2.0, 0.5));
  const float s2c = (float)(beta_fn(800.0 / 2.0, 0.5) / beta_fn(32.0 / 2.0, 0.5));
  const float s3  = (float)(beta_fn(3136.0 / 2.0, 0.5) / beta_fn(64.0 / 2.0, 0.5));
  const float s4  = (float)(beta_fn(1152.0 / 2.0, 0.5) / beta_fn(128.0 / 2.0, 0.5));

  // prep: partial norms, then merged (zfprep + znorm finish)
  znorm_all_kernel<<<dim3(30, 16), 256, 0, stream>>>(z1, z2, z3, z4, zf1, zf2, part);
  zfprep_all_kernel<<<2364, 256, 0, stream>>>(z1, z2, z3, z4, zf1h, zf1l,
                                              zf2h, zf2l, zf3h, zf3l, zf4h, zf4l,
                                              part, zn);

  // ---- layer 1: x (16,3,128,128) -> m1 (16,32,64,64)  [logmap fused]
  hconv_mfma<3, 3, 12, 3, 1, 32, 128, 128, 8, 8, 4, 1, 1, true>
      <<<4096, 256, 0, stream>>>(x, nullptr, zf1h, zf1l, b1, zn + 0, m1, s1b, f1, s1);

  // ---- layer 2: m1 -> m2 (16,64,32,32)
  hconv_mfma<32, 5, 25, 5, 2, 64, 64, 64, 8, 8, 2, 2, 2, false>
      <<<1024, 256, 0, stream>>>(m1, s1b, zf2h, zf2l, b2, zn + 32, m2, s2bf, f2, s2c);

  // ---- layer 3: m2 -> m3 (16,128,16,16)
  hconv_mfma<64, 6, 49, 7, 3, 128, 32, 32, 4, 8, 1, 2, 4, false>
      <<<512, 256, 0, stream>>>(m2, s2bf, zf3h, zf3l, b3, zn + 96, m3, s3b, f3, s3);

  // ---- layer 4: m3 -> m4 (16,128,8,8)
  hconv_mfma<128, 7, 9, 3, 1, 128, 16, 16, 2, 8, 1, 1, 8, false>
      <<<256, 512, 0, stream>>>(m3, s3b, zf4h, zf4l, b4, zn + 224, m4, s4b, f4, s4);

  // ---- features: merged weighted avgpools -> flat (16,352)
  wavgpool_all_kernel<<<dim3(352, 16), 256, 0, stream>>>(
      m1, m2, m3, m4, f1, f2, f3, f4, flat);

  // ---- head
  pfc_y_kernel<352, 512, true, false, 0><<<dim3(8, 16), 256, 0, stream>>>(
      flat, zf1, bf1, zn + 352, yb1, hp1, hpp1, nullptr, nullptr);
  pfc_y_kernel<512, 1000, false, true, 8><<<dim3(16, 16), 256, 0, stream>>>(
      yb1, zf2, bf2, zn + 864, yb2, hp2, nullptr, hp1, hpp1);
  pfc_fin_kernel<1000, 16><<<16, 256, 0, stream>>>(yb2, hp2, outp);

  (void)in_sizes; (void)n_in; (void)out_size; (void)ws_size;
}